// Round 1
// baseline (277.239 us; speedup 1.0000x reference)
//
#include <hip/hip_runtime.h>
#include <hip/hip_bf16.h>
#include <stdint.h>

#define NTOK 392
#define DIM  128
#define NH   4
#define HD   32
#define NKVP 416   // 13*32 padded keys
#define NCH  13
#define KST  36    // K_lds stride (shorts): 18*r mod 32 distinct -> conflict-free
#define VST  420   // Vt_lds stride (shorts): 210 ~ 18d mod 32 distinct

typedef __attribute__((ext_vector_type(4))) float f32x4;
typedef __attribute__((ext_vector_type(4))) short s16x4;
typedef __attribute__((ext_vector_type(8))) short s16x8;

union Frag { s16x8 v; struct { s16x4 lo, hi; } h; };

__device__ __forceinline__ short f2bf(float f) {
  union { float f; uint32_t u; } v; v.f = f;
  uint32_t r = v.u + 0x7fffu + ((v.u >> 16) & 1u);
  return (short)(r >> 16);
}
__device__ __forceinline__ s16x4 cvt4(f32x4 a) {
  s16x4 r; r.x = f2bf(a.x); r.y = f2bf(a.y); r.z = f2bf(a.z); r.w = f2bf(a.w);
  return r;
}

// ---------------- K0: expand relative-position bias to [h][n][m] f32 ----------
__global__ void k_bias(const float* __restrict__ bt, const int* __restrict__ ri,
                       float* __restrict__ bias_pre) {
  int i = blockIdx.x * 256 + threadIdx.x;
  if (i >= NTOK * NTOK) return;
  int idx = ri[i];
  f32x4 t = *(const f32x4*)(bt + 4 * idx);
  bias_pre[i]                   = t.x;
  bias_pre[NTOK*NTOK + i]       = t.y;
  bias_pre[2*NTOK*NTOK + i]     = t.z;
  bias_pre[3*NTOK*NTOK + i]     = t.w;
}

// ---------------- K1: qkv = x @ qkv_w^T, bf16 out, q pre-scaled ---------------
__global__ __launch_bounds__(256, 2)
void k_qkv(const float* __restrict__ x, const float* __restrict__ qkv_w,
           short* __restrict__ q_ws, short* __restrict__ k_ws,
           short* __restrict__ v_ws) {
  __shared__ short xs[64 * 136];
  __shared__ short wl[128 * 136];
  const int t  = threadIdx.x;
  const int z  = blockIdx.y;          // 0=q 1=k 2=v
  const int m0 = blockIdx.x * 64;
  {
    const int r = t >> 2, c0 = (t & 3) * 32;
    const float* src = x + (size_t)(m0 + r) * DIM + c0;
    short* dst = xs + r * 136 + c0;
    #pragma unroll
    for (int i = 0; i < 8; ++i)
      *(s16x4*)(dst + 4*i) = cvt4(*(const f32x4*)(src + 4*i));
  }
  {
    const int r = t >> 1, c0 = (t & 1) * 64;
    const float* src = qkv_w + (size_t)(z * DIM + r) * DIM + c0;
    short* dst = wl + r * 136 + c0;
    #pragma unroll
    for (int i = 0; i < 16; ++i)
      *(s16x4*)(dst + 4*i) = cvt4(*(const f32x4*)(src + 4*i));
  }
  __syncthreads();
  const int l = t & 63, w = t >> 6, lr = l & 15, g = l >> 4;
  f32x4 acc[8] = {};
  #pragma unroll
  for (int ks = 0; ks < 4; ++ks) {
    const int k0 = ks * 32 + 4 * g;
    Frag a;
    const short* ap = xs + (w * 16 + lr) * 136 + k0;
    a.h.lo = *(const s16x4*)ap; a.h.hi = *(const s16x4*)(ap + 16);
    #pragma unroll
    for (int ct = 0; ct < 8; ++ct) {
      const short* bp = wl + (ct * 16 + lr) * 136 + k0;
      Frag bf; bf.h.lo = *(const s16x4*)bp; bf.h.hi = *(const s16x4*)(bp + 16);
      acc[ct] = __builtin_amdgcn_mfma_f32_16x16x32_bf16(a.v, bf.v, acc[ct], 0, 0, 0);
    }
  }
  short* outp = (z == 0) ? q_ws : (z == 1 ? k_ws : v_ws);
  const float scale = (z == 0) ? 0.17677669529663689f : 1.0f;
  #pragma unroll
  for (int ct = 0; ct < 8; ++ct) {
    const int col = ct * 16 + lr;
    const int hh = col >> 5, d = col & 31;
    #pragma unroll
    for (int r = 0; r < 4; ++r) {
      const int m = m0 + w * 16 + 4 * g + r;
      const int b = m / NTOK;
      const int n = m - b * NTOK;
      outp[(((size_t)b * NH + hh) * NTOK + n) * HD + d] = f2bf(acc[ct][r] * scale);
    }
  }
}

// ---------------- K2: per-(window,head) attention -----------------------------
__global__ __launch_bounds__(256, 2)
void k_attn(const short* __restrict__ q_ws, const short* __restrict__ k_ws,
            const short* __restrict__ v_ws, const float* __restrict__ mask,
            const float* __restrict__ bias_pre, short* __restrict__ y_ws) {
  __shared__ short K_l[NKVP * KST];   // [kv][d]
  __shared__ short Vt[HD * VST];      // [d][kv]
  const int t = threadIdx.x;
  // XCD swizzle: 4 heads of one window land on the same XCD, adjacent slots
  const int j = blockIdx.x, xcd = j & 7, slot = j >> 3;
  const int b = (xcd << 5) | (slot >> 2);
  const int h = slot & 3;
  const size_t bh = (size_t)b * NH + h;
  const short* kp = k_ws + bh * NTOK * HD;
  const short* vp = v_ws + bh * NTOK * HD;
  const short* qp = q_ws + bh * NTOK * HD;
  const float* mp = mask + (size_t)b * NTOK * NTOK;
  const float* bp = bias_pre + (size_t)h * NTOK * NTOK;
  // stage K (+ zero pad rows)
  for (int r = t; r < NKVP; r += 256) {
    short* dst = K_l + r * KST;
    if (r < NTOK) {
      const s16x4* src = (const s16x4*)(kp + r * HD);
      #pragma unroll
      for (int i = 0; i < 8; ++i) *(s16x4*)(dst + 4*i) = src[i];
    } else {
      s16x4 zz = {0, 0, 0, 0};
      #pragma unroll
      for (int i = 0; i < 8; ++i) *(s16x4*)(dst + 4*i) = zz;
    }
  }
  // stage V transposed
  for (int n = t; n < NTOK; n += 256) {
    union { s16x4 v4[8]; short s[32]; } vv;
    const s16x4* src = (const s16x4*)(vp + n * HD);
    #pragma unroll
    for (int i = 0; i < 8; ++i) vv.v4[i] = src[i];
    #pragma unroll
    for (int d = 0; d < 32; ++d) Vt[d * VST + n] = vv.s[d];
  }
  // zero pad Vt cols [NTOK, VST)
  for (int i = t; i < HD * (VST - NTOK); i += 256) {
    int d = i / (VST - NTOK), c = NTOK + i % (VST - NTOK);
    Vt[d * VST + c] = 0;
  }
  __syncthreads();
  const int l = t & 63, w = t >> 6, lr = l & 15, g = l >> 4;
  #pragma unroll 1
  for (int q0 = w * 16; q0 < NTOK; q0 += 64) {
    const int qrow = q0 + lr;
    const int qc = qrow < NTOK ? qrow : NTOK - 1;
    Frag qf;
    { const short* qa = qp + qc * HD + 4 * g;
      qf.h.lo = *(const s16x4*)qa; qf.h.hi = *(const s16x4*)(qa + 16); }
    const float* mrow = mp + (size_t)qc * NTOK;
    const float* brow = bp + (size_t)qc * NTOK;
    f32x4 o0 = {0,0,0,0}, o1 = {0,0,0,0};
    float mrun = -1e30f, lrun = 0.f;
    f32x4 mb0, mb1, nb0, nb1;
    {
      int cb0 = 4 * g, cb1 = 16 + 4 * g;
      mb0 = *(const f32x4*)(mrow + cb0) + *(const f32x4*)(brow + cb0);
      mb1 = *(const f32x4*)(mrow + cb1) + *(const f32x4*)(brow + cb1);
    }
    #pragma unroll 1
    for (int c = 0; c < NCH; ++c) {
      const int kv0 = c * 32;
      // prefetch next chunk's mask+bias
      {
        int c2 = (c + 1 < NCH) ? c + 1 : c;
        int cb0 = c2 * 32 + 4 * g;      if (cb0 > NTOK - 4) cb0 = NTOK - 4;
        int cb1 = c2 * 32 + 16 + 4 * g; if (cb1 > NTOK - 4) cb1 = NTOK - 4;
        nb0 = *(const f32x4*)(mrow + cb0) + *(const f32x4*)(brow + cb0);
        nb1 = *(const f32x4*)(mrow + cb1) + *(const f32x4*)(brow + cb1);
      }
      // S^T = K . Q^T   (lane: q = lr, kv = kv0 + 4g + r  /  +16)
      Frag ka0, ka1;
      { const short* p0 = K_l + (kv0 + lr) * KST + 4 * g;
        ka0.h.lo = *(const s16x4*)p0; ka0.h.hi = *(const s16x4*)(p0 + 16);
        const short* p1 = K_l + (kv0 + 16 + lr) * KST + 4 * g;
        ka1.h.lo = *(const s16x4*)p1; ka1.h.hi = *(const s16x4*)(p1 + 16); }
      f32x4 zero4 = {0,0,0,0};
      f32x4 s0 = __builtin_amdgcn_mfma_f32_16x16x32_bf16(ka0.v, qf.v, zero4, 0,0,0);
      f32x4 s1 = __builtin_amdgcn_mfma_f32_16x16x32_bf16(ka1.v, qf.v, zero4, 0,0,0);
      float sv[8];
      #pragma unroll
      for (int r = 0; r < 4; ++r) {
        sv[r]     = (kv0 + 4*g + r      < NTOK) ? (s0[r] + mb0[r]) : -1e30f;
        sv[4 + r] = (kv0 + 16 + 4*g + r < NTOK) ? (s1[r] + mb1[r]) : -1e30f;
      }
      // online softmax (q lives on lane&15 for S, O and stats: no permutes)
      float cm = sv[0];
      #pragma unroll
      for (int i = 1; i < 8; ++i) cm = fmaxf(cm, sv[i]);
      cm = fmaxf(cm, __shfl_xor(cm, 16));
      cm = fmaxf(cm, __shfl_xor(cm, 32));
      const float mnew = fmaxf(mrun, cm);
      const float alpha = __expf(mrun - mnew);
      float p[8], cs = 0.f;
      #pragma unroll
      for (int i = 0; i < 8; ++i) { p[i] = __expf(sv[i] - mnew); cs += p[i]; }
      cs += __shfl_xor(cs, 16);
      cs += __shfl_xor(cs, 32);
      lrun = lrun * alpha + cs;
      mrun = mnew;
      #pragma unroll
      for (int r = 0; r < 4; ++r) { o0[r] *= alpha; o1[r] *= alpha; }
      Frag pf;
      pf.h.lo.x = f2bf(p[0]); pf.h.lo.y = f2bf(p[1]);
      pf.h.lo.z = f2bf(p[2]); pf.h.lo.w = f2bf(p[3]);
      pf.h.hi.x = f2bf(p[4]); pf.h.hi.y = f2bf(p[5]);
      pf.h.hi.z = f2bf(p[6]); pf.h.hi.w = f2bf(p[7]);
      Frag vf0, vf1;
      { const short* v0 = Vt + lr * VST + kv0 + 4 * g;
        vf0.h.lo = *(const s16x4*)v0; vf0.h.hi = *(const s16x4*)(v0 + 16);
        const short* v1 = Vt + (16 + lr) * VST + kv0 + 4 * g;
        vf1.h.lo = *(const s16x4*)v1; vf1.h.hi = *(const s16x4*)(v1 + 16); }
      // O^T = V^T . P^T : P frag comes straight from s0/s1 register layout
      o0 = __builtin_amdgcn_mfma_f32_16x16x32_bf16(vf0.v, pf.v, o0, 0,0,0);
      o1 = __builtin_amdgcn_mfma_f32_16x16x32_bf16(vf1.v, pf.v, o1, 0,0,0);
      mb0 = nb0; mb1 = nb1;
    }
    if (qrow < NTOK) {
      const float inv = 1.0f / lrun;
      short* yb = y_ws + ((size_t)b * NTOK + qrow) * DIM + h * HD;
      s16x4 r0, r1;
      #pragma unroll
      for (int r = 0; r < 4; ++r) { r0[r] = f2bf(o0[r] * inv); r1[r] = f2bf(o1[r] * inv); }
      *(s16x4*)(yb + 4 * g) = r0;
      *(s16x4*)(yb + 16 + 4 * g) = r1;
    }
  }
}

// ---------------- K3: out = y @ proj_w^T + proj_b -----------------------------
__global__ __launch_bounds__(256, 2)
void k_proj(const short* __restrict__ y_ws, const float* __restrict__ pw,
            const float* __restrict__ pb, float* __restrict__ out) {
  __shared__ short ys[64 * 136];
  __shared__ short wl[128 * 136];
  const int t = threadIdx.x;
  const int m0 = blockIdx.x * 64;
  {
    const int r = t >> 2, c0 = (t & 3) * 32;
    const s16x4* src = (const s16x4*)(y_ws + (size_t)(m0 + r) * DIM + c0);
    short* dst = ys + r * 136 + c0;
    #pragma unroll
    for (int i = 0; i < 8; ++i) *(s16x4*)(dst + 4*i) = src[i];
  }
  {
    const int r = t >> 1, c0 = (t & 1) * 64;
    const float* src = pw + (size_t)r * DIM + c0;
    short* dst = wl + r * 136 + c0;
    #pragma unroll
    for (int i = 0; i < 16; ++i)
      *(s16x4*)(dst + 4*i) = cvt4(*(const f32x4*)(src + 4*i));
  }
  __syncthreads();
  const int l = t & 63, w = t >> 6, lr = l & 15, g = l >> 4;
  f32x4 acc[8] = {};
  #pragma unroll
  for (int ks = 0; ks < 4; ++ks) {
    const int k0 = ks * 32 + 4 * g;
    Frag a;
    const short* ap = ys + (w * 16 + lr) * 136 + k0;
    a.h.lo = *(const s16x4*)ap; a.h.hi = *(const s16x4*)(ap + 16);
    #pragma unroll
    for (int ct = 0; ct < 8; ++ct) {
      const short* bpp = wl + (ct * 16 + lr) * 136 + k0;
      Frag bf; bf.h.lo = *(const s16x4*)bpp; bf.h.hi = *(const s16x4*)(bpp + 16);
      acc[ct] = __builtin_amdgcn_mfma_f32_16x16x32_bf16(a.v, bf.v, acc[ct], 0, 0, 0);
    }
  }
  #pragma unroll
  for (int ct = 0; ct < 8; ++ct) {
    const int col = ct * 16 + lr;
    const float bias = pb[col];
    #pragma unroll
    for (int r = 0; r < 4; ++r) {
      const int m = m0 + w * 16 + 4 * g + r;
      out[(size_t)m * DIM + col] = acc[ct][r] + bias;
    }
  }
}

extern "C" void kernel_launch(void* const* d_in, const int* in_sizes, int n_in,
                              void* d_out, int out_size, void* d_ws, size_t ws_size,
                              hipStream_t stream) {
  const float* x    = (const float*)d_in[0];
  const float* mask = (const float*)d_in[1];
  const float* bt   = (const float*)d_in[2];
  const int*   ri   = (const int*)d_in[3];
  const float* qkvw = (const float*)d_in[4];
  const float* pw   = (const float*)d_in[5];
  const float* pb   = (const float*)d_in[6];
  float* out = (float*)d_out;
  // ws layout (bytes): 4 x 25.69MB bf16 tensors + 2.46MB bias = ~105.2MB
  const size_t TEN = (size_t)256 * NH * NTOK * HD;   // 12,845,056
  short* q_ws = (short*)d_ws;
  short* k_ws = q_ws + TEN;
  short* v_ws = k_ws + TEN;
  short* y_ws = v_ws + TEN;
  float* bias_pre = (float*)(y_ws + TEN);
  k_bias<<<(NTOK * NTOK + 255) / 256, 256, 0, stream>>>(bt, ri, bias_pre);
  k_qkv<<<dim3(1568, 3), 256, 0, stream>>>(x, qkvw, q_ws, k_ws, v_ws);
  k_attn<<<1024, 256, 0, stream>>>(q_ws, k_ws, v_ws, mask, bias_pre, y_ws);
  k_proj<<<1568, 256, 0, stream>>>(y_ws, pw, pb, out);
}

// Round 2
// 267.737 us; speedup vs baseline: 1.0355x; 1.0355x over previous
//
#include <hip/hip_runtime.h>
#include <hip/hip_bf16.h>
#include <stdint.h>

#define NTOK 392
#define DIM  128
#define NH   4
#define HD   32
#define NKVP 416   // 13*32 padded keys
#define NCH  13
#define KST  36    // K_lds stride (shorts): 18*r mod 32 distinct -> conflict-free
#define VST  420   // Vt_lds stride (shorts): 210 dwords; 18d mod 32 distinct

typedef __attribute__((ext_vector_type(4))) float f32x4;
typedef __attribute__((ext_vector_type(4))) short s16x4;
typedef __attribute__((ext_vector_type(8))) short s16x8;

union Frag { s16x8 v; struct { s16x4 lo, hi; } h; };

__device__ __forceinline__ short f2bf(float f) {
  union { float f; uint32_t u; } v; v.f = f;
  uint32_t r = v.u + 0x7fffu + ((v.u >> 16) & 1u);
  return (short)(r >> 16);
}
__device__ __forceinline__ s16x4 cvt4(f32x4 a) {
  s16x4 r; r.x = f2bf(a.x); r.y = f2bf(a.y); r.z = f2bf(a.z); r.w = f2bf(a.w);
  return r;
}

// ---------------- K0: expand relative-position bias to [h][n][m] f32 ----------
__global__ void k_bias(const float* __restrict__ bt, const int* __restrict__ ri,
                       float* __restrict__ bias_pre) {
  int i = blockIdx.x * 256 + threadIdx.x;
  if (i >= NTOK * NTOK) return;
  int idx = ri[i];
  f32x4 t = *(const f32x4*)(bt + 4 * idx);
  bias_pre[i]                   = t.x;
  bias_pre[NTOK*NTOK + i]       = t.y;
  bias_pre[2*NTOK*NTOK + i]     = t.z;
  bias_pre[3*NTOK*NTOK + i]     = t.w;
}

// ------- K1: qkv = x @ qkv_w^T, bf16 out, q pre-scaled; fused z-loop ---------
__global__ __launch_bounds__(256, 2)
void k_qkv(const float* __restrict__ x, const float* __restrict__ qkv_w,
           short* __restrict__ q_ws, short* __restrict__ k_ws,
           short* __restrict__ v_ws) {
  __shared__ short xs[64 * 136];
  __shared__ short wl[128 * 136];
  const int t  = threadIdx.x;
  const int m0 = blockIdx.x * 64;
  {
    const int r = t >> 2, c0 = (t & 3) * 32;
    const float* src = x + (size_t)(m0 + r) * DIM + c0;
    short* dst = xs + r * 136 + c0;
    #pragma unroll
    for (int i = 0; i < 8; ++i)
      *(s16x4*)(dst + 4*i) = cvt4(*(const f32x4*)(src + 4*i));
  }
  const int l = t & 63, w = t >> 6, lr = l & 15, g = l >> 4;
  #pragma unroll 1
  for (int z = 0; z < 3; ++z) {
    {
      const int r = t >> 1, c0 = (t & 1) * 64;
      const float* src = qkv_w + (size_t)(z * DIM + r) * DIM + c0;
      short* dst = wl + r * 136 + c0;
      #pragma unroll
      for (int i = 0; i < 16; ++i)
        *(s16x4*)(dst + 4*i) = cvt4(*(const f32x4*)(src + 4*i));
    }
    __syncthreads();
    f32x4 acc[8] = {};
    #pragma unroll
    for (int ks = 0; ks < 4; ++ks) {
      const int k0 = ks * 32 + 4 * g;
      Frag a;
      const short* ap = xs + (w * 16 + lr) * 136 + k0;
      a.h.lo = *(const s16x4*)ap; a.h.hi = *(const s16x4*)(ap + 16);
      #pragma unroll
      for (int ct = 0; ct < 8; ++ct) {
        const short* bp = wl + (ct * 16 + lr) * 136 + k0;
        Frag bf; bf.h.lo = *(const s16x4*)bp; bf.h.hi = *(const s16x4*)(bp + 16);
        acc[ct] = __builtin_amdgcn_mfma_f32_16x16x32_bf16(a.v, bf.v, acc[ct], 0, 0, 0);
      }
    }
    short* outp = (z == 0) ? q_ws : (z == 1 ? k_ws : v_ws);
    const float scale = (z == 0) ? 0.17677669529663689f : 1.0f;
    #pragma unroll
    for (int ct = 0; ct < 8; ++ct) {
      const int col = ct * 16 + lr;
      const int hh = col >> 5, d = col & 31;
      #pragma unroll
      for (int r = 0; r < 4; ++r) {
        const int m = m0 + w * 16 + 4 * g + r;
        const int b = m / NTOK;
        const int n = m - b * NTOK;
        outp[(((size_t)b * NH + hh) * NTOK + n) * HD + d] = f2bf(acc[ct][r] * scale);
      }
    }
    __syncthreads();
  }
}

// ---------------- K2: per-(window,head) attention, 8-wave blocks --------------
__global__ __launch_bounds__(512, 4)
void k_attn(const short* __restrict__ q_ws, const short* __restrict__ k_ws,
            const short* __restrict__ v_ws, const float* __restrict__ mask,
            const float* __restrict__ bias_pre, short* __restrict__ y_ws) {
  __shared__ short K_l[NKVP * KST];   // [kv][d]
  __shared__ short Vt[HD * VST];      // [d][kv]
  const int t = threadIdx.x;
  // XCD swizzle: 4 heads of one window land on the same XCD, adjacent slots
  const int j = blockIdx.x, xcd = j & 7, slot = j >> 3;
  const int b = (xcd << 5) | (slot >> 2);
  const int h = slot & 3;
  const size_t bh = (size_t)b * NH + h;
  const short* kp = k_ws + bh * NTOK * HD;
  const short* vp = v_ws + bh * NTOK * HD;
  const short* qp = q_ws + bh * NTOK * HD;
  const float* mp = mask + (size_t)b * NTOK * NTOK;
  const float* bp = bias_pre + (size_t)h * NTOK * NTOK;
  // stage K (+ zero pad rows)
  for (int r = t; r < NKVP; r += 512) {
    short* dst = K_l + r * KST;
    if (r < NTOK) {
      const s16x4* src = (const s16x4*)(kp + r * HD);
      #pragma unroll
      for (int i = 0; i < 8; ++i) *(s16x4*)(dst + 4*i) = src[i];
    } else {
      s16x4 zz = {0, 0, 0, 0};
      #pragma unroll
      for (int i = 0; i < 8; ++i) *(s16x4*)(dst + 4*i) = zz;
    }
  }
  // stage V transposed
  for (int n = t; n < NTOK; n += 512) {
    union { s16x4 v4[8]; short s[32]; } vv;
    const s16x4* src = (const s16x4*)(vp + n * HD);
    #pragma unroll
    for (int i = 0; i < 8; ++i) vv.v4[i] = src[i];
    #pragma unroll
    for (int d = 0; d < 32; ++d) Vt[d * VST + n] = vv.s[d];
  }
  // zero pad Vt cols [NTOK, VST)
  for (int i = t; i < HD * (VST - NTOK); i += 512) {
    int d = i / (VST - NTOK), c = NTOK + i % (VST - NTOK);
    Vt[d * VST + c] = 0;
  }
  __syncthreads();
  const int l = t & 63, w = t >> 6, lr = l & 15, g = l >> 4;
  #pragma unroll 1
  for (int q0 = w * 16; q0 < NTOK; q0 += 128) {
    const int qrow = q0 + lr;
    const int qc = qrow < NTOK ? qrow : NTOK - 1;
    Frag qf;
    { const short* qa = qp + qc * HD + 4 * g;
      qf.h.lo = *(const s16x4*)qa; qf.h.hi = *(const s16x4*)(qa + 16); }
    const float* mrow = mp + (size_t)qc * NTOK;
    const float* brow = bp + (size_t)qc * NTOK;
    f32x4 o0 = {0,0,0,0}, o1 = {0,0,0,0};
    float mrun = -1e30f, lrun = 0.f;
    f32x4 mb0, mb1, nb0, nb1;
    {
      int cb0 = 4 * g, cb1 = 16 + 4 * g;
      mb0 = *(const f32x4*)(mrow + cb0) + *(const f32x4*)(brow + cb0);
      mb1 = *(const f32x4*)(mrow + cb1) + *(const f32x4*)(brow + cb1);
    }
    #pragma unroll 1
    for (int c = 0; c < NCH; ++c) {
      const int kv0 = c * 32;
      // prefetch next chunk's mask+bias
      {
        int c2 = (c + 1 < NCH) ? c + 1 : c;
        int cb0 = c2 * 32 + 4 * g;      if (cb0 > NTOK - 4) cb0 = NTOK - 4;
        int cb1 = c2 * 32 + 16 + 4 * g; if (cb1 > NTOK - 4) cb1 = NTOK - 4;
        nb0 = *(const f32x4*)(mrow + cb0) + *(const f32x4*)(brow + cb0);
        nb1 = *(const f32x4*)(mrow + cb1) + *(const f32x4*)(brow + cb1);
      }
      // S^T = K . Q^T   (lane: q = lr, kv = kv0 + 4g + r  /  +16)
      Frag ka0, ka1;
      { const short* p0 = K_l + (kv0 + lr) * KST + 4 * g;
        ka0.h.lo = *(const s16x4*)p0; ka0.h.hi = *(const s16x4*)(p0 + 16);
        const short* p1 = K_l + (kv0 + 16 + lr) * KST + 4 * g;
        ka1.h.lo = *(const s16x4*)p1; ka1.h.hi = *(const s16x4*)(p1 + 16); }
      f32x4 zero4 = {0,0,0,0};
      f32x4 s0 = __builtin_amdgcn_mfma_f32_16x16x32_bf16(ka0.v, qf.v, zero4, 0,0,0);
      f32x4 s1 = __builtin_amdgcn_mfma_f32_16x16x32_bf16(ka1.v, qf.v, zero4, 0,0,0);
      float sv[8];
      #pragma unroll
      for (int r = 0; r < 4; ++r) {
        sv[r]     = (kv0 + 4*g + r      < NTOK) ? (s0[r] + mb0[r]) : -1e30f;
        sv[4 + r] = (kv0 + 16 + 4*g + r < NTOK) ? (s1[r] + mb1[r]) : -1e30f;
      }
      // online softmax (q lives on lane&15 for S, O and stats: no permutes)
      float cm = sv[0];
      #pragma unroll
      for (int i = 1; i < 8; ++i) cm = fmaxf(cm, sv[i]);
      cm = fmaxf(cm, __shfl_xor(cm, 16));
      cm = fmaxf(cm, __shfl_xor(cm, 32));
      const float mnew = fmaxf(mrun, cm);
      const float alpha = __expf(mrun - mnew);
      float p[8], cs = 0.f;
      #pragma unroll
      for (int i = 0; i < 8; ++i) { p[i] = __expf(sv[i] - mnew); cs += p[i]; }
      cs += __shfl_xor(cs, 16);
      cs += __shfl_xor(cs, 32);
      lrun = lrun * alpha + cs;
      mrun = mnew;
      #pragma unroll
      for (int r = 0; r < 4; ++r) { o0[r] *= alpha; o1[r] *= alpha; }
      Frag pf;
      pf.h.lo.x = f2bf(p[0]); pf.h.lo.y = f2bf(p[1]);
      pf.h.lo.z = f2bf(p[2]); pf.h.lo.w = f2bf(p[3]);
      pf.h.hi.x = f2bf(p[4]); pf.h.hi.y = f2bf(p[5]);
      pf.h.hi.z = f2bf(p[6]); pf.h.hi.w = f2bf(p[7]);
      Frag vf0, vf1;
      { const short* v0 = Vt + lr * VST + kv0 + 4 * g;
        vf0.h.lo = *(const s16x4*)v0; vf0.h.hi = *(const s16x4*)(v0 + 16);
        const short* v1 = Vt + (16 + lr) * VST + kv0 + 4 * g;
        vf1.h.lo = *(const s16x4*)v1; vf1.h.hi = *(const s16x4*)(v1 + 16); }
      // O^T = V^T . P^T : P frag comes straight from s0/s1 register layout
      o0 = __builtin_amdgcn_mfma_f32_16x16x32_bf16(vf0.v, pf.v, o0, 0,0,0);
      o1 = __builtin_amdgcn_mfma_f32_16x16x32_bf16(vf1.v, pf.v, o1, 0,0,0);
      mb0 = nb0; mb1 = nb1;
    }
    if (qrow < NTOK) {
      const float inv = 1.0f / lrun;
      short* yb = y_ws + ((size_t)b * NTOK + qrow) * DIM + h * HD;
      s16x4 r0, r1;
      #pragma unroll
      for (int r = 0; r < 4; ++r) { r0[r] = f2bf(o0[r] * inv); r1[r] = f2bf(o1[r] * inv); }
      *(s16x4*)(yb + 4 * g) = r0;
      *(s16x4*)(yb + 16 + 4 * g) = r1;
    }
  }
}

// ---------------- K3: out = y @ proj_w^T + proj_b -----------------------------
__global__ __launch_bounds__(256, 2)
void k_proj(const short* __restrict__ y_ws, const float* __restrict__ pw,
            const float* __restrict__ pb, float* __restrict__ out) {
  __shared__ short ys[64 * 136];
  __shared__ short wl[128 * 136];
  const int t = threadIdx.x;
  const int m0 = blockIdx.x * 64;
  {
    const int r = t >> 2, c0 = (t & 3) * 32;
    const s16x4* src = (const s16x4*)(y_ws + (size_t)(m0 + r) * DIM + c0);
    short* dst = ys + r * 136 + c0;
    #pragma unroll
    for (int i = 0; i < 8; ++i) *(s16x4*)(dst + 4*i) = src[i];
  }
  {
    const int r = t >> 1, c0 = (t & 1) * 64;
    const float* src = pw + (size_t)r * DIM + c0;
    short* dst = wl + r * 136 + c0;
    #pragma unroll
    for (int i = 0; i < 16; ++i)
      *(s16x4*)(dst + 4*i) = cvt4(*(const f32x4*)(src + 4*i));
  }
  __syncthreads();
  const int l = t & 63, w = t >> 6, lr = l & 15, g = l >> 4;
  f32x4 acc[8] = {};
  #pragma unroll
  for (int ks = 0; ks < 4; ++ks) {
    const int k0 = ks * 32 + 4 * g;
    Frag a;
    const short* ap = ys + (w * 16 + lr) * 136 + k0;
    a.h.lo = *(const s16x4*)ap; a.h.hi = *(const s16x4*)(ap + 16);
    #pragma unroll
    for (int ct = 0; ct < 8; ++ct) {
      const short* bpp = wl + (ct * 16 + lr) * 136 + k0;
      Frag bf; bf.h.lo = *(const s16x4*)bpp; bf.h.hi = *(const s16x4*)(bpp + 16);
      acc[ct] = __builtin_amdgcn_mfma_f32_16x16x32_bf16(a.v, bf.v, acc[ct], 0, 0, 0);
    }
  }
  #pragma unroll
  for (int ct = 0; ct < 8; ++ct) {
    const int col = ct * 16 + lr;
    const float bias = pb[col];
    #pragma unroll
    for (int r = 0; r < 4; ++r) {
      const int m = m0 + w * 16 + 4 * g + r;
      out[(size_t)m * DIM + col] = acc[ct][r] + bias;
    }
  }
}

extern "C" void kernel_launch(void* const* d_in, const int* in_sizes, int n_in,
                              void* d_out, int out_size, void* d_ws, size_t ws_size,
                              hipStream_t stream) {
  const float* x    = (const float*)d_in[0];
  const float* mask = (const float*)d_in[1];
  const float* bt   = (const float*)d_in[2];
  const int*   ri   = (const int*)d_in[3];
  const float* qkvw = (const float*)d_in[4];
  const float* pw   = (const float*)d_in[5];
  const float* pb   = (const float*)d_in[6];
  float* out = (float*)d_out;
  // ws layout (bytes): 4 x 25.69MB bf16 tensors + 2.46MB bias = ~105.2MB
  const size_t TEN = (size_t)256 * NH * NTOK * HD;   // 12,845,056
  short* q_ws = (short*)d_ws;
  short* k_ws = q_ws + TEN;
  short* v_ws = k_ws + TEN;
  short* y_ws = v_ws + TEN;
  float* bias_pre = (float*)(y_ws + TEN);
  k_bias<<<(NTOK * NTOK + 255) / 256, 256, 0, stream>>>(bt, ri, bias_pre);
  k_qkv<<<1568, 256, 0, stream>>>(x, qkvw, q_ws, k_ws, v_ws);
  k_attn<<<1024, 512, 0, stream>>>(q_ws, k_ws, v_ws, mask, bias_pre, y_ws);
  k_proj<<<1568, 256, 0, stream>>>(y_ws, pw, pb, out);
}

// Round 3
// 262.347 us; speedup vs baseline: 1.0568x; 1.0205x over previous
//
#include <hip/hip_runtime.h>
#include <hip/hip_bf16.h>
#include <stdint.h>

#define NTOK 392
#define DIM  128
#define NH   4
#define HD   32
#define NKVP 416   // 13*32 padded keys
#define NCH  13
#define KST  36    // K_lds stride (shorts): 18*r mod 32 distinct -> conflict-free
#define VST  420   // Vt_lds stride (shorts): 210 dwords; 18d mod 32 distinct
#define L2E  1.44269504f

typedef __attribute__((ext_vector_type(4))) float f32x4;
typedef __attribute__((ext_vector_type(4))) short s16x4;
typedef __attribute__((ext_vector_type(8))) short s16x8;

union Frag { s16x8 v; struct { s16x4 lo, hi; } h; };
union PF { s16x8 v; uint32_t u[4]; };

__device__ __forceinline__ short f2bf(float f) {
  union { float f; uint32_t u; } v; v.f = f;
  uint32_t r = v.u + 0x7fffu + ((v.u >> 16) & 1u);
  return (short)(r >> 16);
}
__device__ __forceinline__ s16x4 cvt4(f32x4 a) {
  s16x4 r; r.x = f2bf(a.x); r.y = f2bf(a.y); r.z = f2bf(a.z); r.w = f2bf(a.w);
  return r;
}

// ---------------- K0: expand relative-position bias to [h][n][m] f32 ----------
__global__ void k_bias(const float* __restrict__ bt, const int* __restrict__ ri,
                       float* __restrict__ bias_pre) {
  int i = blockIdx.x * 256 + threadIdx.x;
  if (i >= NTOK * NTOK) return;
  int idx = ri[i];
  f32x4 t = *(const f32x4*)(bt + 4 * idx);
  bias_pre[i]                   = t.x;
  bias_pre[NTOK*NTOK + i]       = t.y;
  bias_pre[2*NTOK*NTOK + i]     = t.z;
  bias_pre[3*NTOK*NTOK + i]     = t.w;
}

// ------- K1: qkv = x @ qkv_w^T, bf16 out, q pre-scaled; fused z-loop ---------
// Swapped MFMA operands: D[c][m] so each lane owns 4 consecutive channels ->
// 8-byte s16x4 stores instead of 32 scalar 2B stores.
__global__ __launch_bounds__(256, 2)
void k_qkv(const float* __restrict__ x, const float* __restrict__ qkv_w,
           short* __restrict__ q_ws, short* __restrict__ k_ws,
           short* __restrict__ v_ws) {
  __shared__ short xs[64 * 136];
  __shared__ short wl[128 * 136];
  const int t  = threadIdx.x;
  const int m0 = blockIdx.x * 64;
  {
    const int r = t >> 2, c0 = (t & 3) * 32;
    const float* src = x + (size_t)(m0 + r) * DIM + c0;
    short* dst = xs + r * 136 + c0;
    #pragma unroll
    for (int i = 0; i < 8; ++i)
      *(s16x4*)(dst + 4*i) = cvt4(*(const f32x4*)(src + 4*i));
  }
  const int l = t & 63, w = t >> 6, lr = l & 15, g = l >> 4;
  const int m = m0 + w * 16 + lr;
  const int b = m / NTOK;
  const int n = m - b * NTOK;
  #pragma unroll 1
  for (int z = 0; z < 3; ++z) {
    {
      const int r = t >> 1, c0 = (t & 1) * 64;
      const float* src = qkv_w + (size_t)(z * DIM + r) * DIM + c0;
      short* dst = wl + r * 136 + c0;
      #pragma unroll
      for (int i = 0; i < 16; ++i)
        *(s16x4*)(dst + 4*i) = cvt4(*(const f32x4*)(src + 4*i));
    }
    __syncthreads();
    f32x4 acc[8] = {};
    #pragma unroll
    for (int ks = 0; ks < 4; ++ks) {
      const int k0 = ks * 32 + 4 * g;
      Frag xb;
      const short* bp = xs + (w * 16 + lr) * 136 + k0;
      xb.h.lo = *(const s16x4*)bp; xb.h.hi = *(const s16x4*)(bp + 16);
      #pragma unroll
      for (int ct = 0; ct < 8; ++ct) {
        const short* ap = wl + (ct * 16 + lr) * 136 + k0;
        Frag wa; wa.h.lo = *(const s16x4*)ap; wa.h.hi = *(const s16x4*)(ap + 16);
        acc[ct] = __builtin_amdgcn_mfma_f32_16x16x32_bf16(wa.v, xb.v, acc[ct], 0, 0, 0);
      }
    }
    short* outp = (z == 0) ? q_ws : (z == 1 ? k_ws : v_ws);
    const float scale = (z == 0) ? 0.17677669529663689f : 1.0f;
    #pragma unroll
    for (int ct = 0; ct < 8; ++ct) {
      const int c0 = ct * 16 + 4 * g;       // 4 consecutive channels
      const int hh = c0 >> 5, d = c0 & 31;
      f32x4 sc = acc[ct];
      sc.x *= scale; sc.y *= scale; sc.z *= scale; sc.w *= scale;
      *(s16x4*)(outp + (((size_t)b * NH + hh) * NTOK + n) * HD + d) = cvt4(sc);
    }
    __syncthreads();
  }
}

// ---------------- K2: per-(window,head) attention, 8-wave blocks --------------
// Defer-max online softmax: wave-common mrun (rarely updated), per-lane
// partial lrun, zero cross-lane traffic in the common path.
__global__ __launch_bounds__(512, 4)
void k_attn(const short* __restrict__ q_ws, const short* __restrict__ k_ws,
            const short* __restrict__ v_ws, const float* __restrict__ mask,
            const float* __restrict__ bias_pre, short* __restrict__ y_ws) {
  __shared__ short K_l[NKVP * KST];   // [kv][d]
  __shared__ short Vt[HD * VST];      // [d][kv]
  const int t = threadIdx.x;
  // XCD swizzle: 4 heads of one window land on the same XCD, adjacent slots
  const int j = blockIdx.x, xcd = j & 7, slot = j >> 3;
  const int b = (xcd << 5) | (slot >> 2);
  const int h = slot & 3;
  const size_t bh = (size_t)b * NH + h;
  const short* kp = k_ws + bh * NTOK * HD;
  const short* vp = v_ws + bh * NTOK * HD;
  const short* qp = q_ws + bh * NTOK * HD;
  const float* mp = mask + (size_t)b * NTOK * NTOK;
  const float* bp = bias_pre + (size_t)h * NTOK * NTOK;
  // stage K (+ zero pad rows)
  for (int r = t; r < NKVP; r += 512) {
    short* dst = K_l + r * KST;
    if (r < NTOK) {
      const s16x4* src = (const s16x4*)(kp + r * HD);
      #pragma unroll
      for (int i = 0; i < 8; ++i) *(s16x4*)(dst + 4*i) = src[i];
    } else {
      s16x4 zz = {0, 0, 0, 0};
      #pragma unroll
      for (int i = 0; i < 8; ++i) *(s16x4*)(dst + 4*i) = zz;
    }
  }
  // stage V transposed
  for (int n = t; n < NTOK; n += 512) {
    union { s16x4 v4[8]; short s[32]; } vv;
    const s16x4* src = (const s16x4*)(vp + n * HD);
    #pragma unroll
    for (int i = 0; i < 8; ++i) vv.v4[i] = src[i];
    #pragma unroll
    for (int d = 0; d < 32; ++d) Vt[d * VST + n] = vv.s[d];
  }
  // zero pad Vt cols [NTOK, VST)
  for (int i = t; i < HD * (VST - NTOK); i += 512) {
    int d = i / (VST - NTOK), c = NTOK + i % (VST - NTOK);
    Vt[d * VST + c] = 0;
  }
  __syncthreads();
  const int l = t & 63, w = t >> 6, lr = l & 15, g = l >> 4;
  const int og0 = 4 * g, og1 = 16 + 4 * g;
  #pragma unroll 1
  for (int q0 = w * 16; q0 < NTOK; q0 += 128) {
    const int qrow = q0 + lr;
    const int qc = qrow < NTOK ? qrow : NTOK - 1;
    Frag qf;
    { const short* qa = qp + qc * HD + 4 * g;
      qf.h.lo = *(const s16x4*)qa; qf.h.hi = *(const s16x4*)(qa + 16); }
    const float* mrow = mp + (size_t)qc * NTOK;
    const float* brow = bp + (size_t)qc * NTOK;
    f32x4 o0 = {0,0,0,0}, o1 = {0,0,0,0};
    float mrun = 0.f, nmrl = 0.f, lrun = 0.f;
    f32x4 mb0, mb1, nb0, nb1;
    mb0 = *(const f32x4*)(mrow + og0) + *(const f32x4*)(brow + og0);
    mb1 = *(const f32x4*)(mrow + og1) + *(const f32x4*)(brow + og1);
    #pragma unroll 1
    for (int c = 0; c < NCH; ++c) {
      const int kv0 = c * 32;
      // prefetch next chunk's mask+bias (tail chunk: poison pads to -3e30)
      if (c < NCH - 2) {
        const int b0 = kv0 + 32 + og0, b1 = kv0 + 32 + og1;
        nb0 = *(const f32x4*)(mrow + b0) + *(const f32x4*)(brow + b0);
        nb1 = *(const f32x4*)(mrow + b1) + *(const f32x4*)(brow + b1);
      } else if (c == NCH - 2) {
        const f32x4 neg = {-3e30f, -3e30f, -3e30f, -3e30f};
        int b0 = 384 + og0; if (b0 > NTOK - 4) b0 = NTOK - 4;
        f32x4 tv = *(const f32x4*)(mrow + b0) + *(const f32x4*)(brow + b0);
        nb0 = (g < 2) ? tv : neg;   // kv 384..391 real, 392..399 pad
        nb1 = neg;                  // kv 400..415 all pad
      }
      // S^T = K . Q^T   (lane: q = lr, kv = kv0 + 4g + r  /  +16)
      Frag ka0, ka1;
      { const short* p0 = K_l + (kv0 + lr) * KST + 4 * g;
        ka0.h.lo = *(const s16x4*)p0; ka0.h.hi = *(const s16x4*)(p0 + 16);
        const short* p1 = K_l + (kv0 + 16 + lr) * KST + 4 * g;
        ka1.h.lo = *(const s16x4*)p1; ka1.h.hi = *(const s16x4*)(p1 + 16); }
      f32x4 zero4 = {0,0,0,0};
      f32x4 s0 = __builtin_amdgcn_mfma_f32_16x16x32_bf16(ka0.v, qf.v, zero4, 0,0,0);
      f32x4 s1 = __builtin_amdgcn_mfma_f32_16x16x32_bf16(ka1.v, qf.v, zero4, 0,0,0);
      s0 += mb0; s1 += mb1;
      // per-lane max only; cross-lane work deferred behind a rare guard
      float cm = fmaxf(fmaxf(fmaxf(s0.x, s0.y), fmaxf(s0.z, s0.w)),
                       fmaxf(fmaxf(s1.x, s1.y), fmaxf(s1.z, s1.w)));
      if (__any(cm > mrun + 8.f)) {         // rare: true running-max rescale
        float tmx = fmaxf(cm, __shfl_xor(cm, 16));
        tmx = fmaxf(tmx, __shfl_xor(tmx, 32));
        const float mnew = fmaxf(mrun, tmx);
        const float al = exp2f((mrun - mnew) * L2E);
        #pragma unroll
        for (int r = 0; r < 4; ++r) { o0[r] *= al; o1[r] *= al; }
        lrun *= al; mrun = mnew; nmrl = -mnew * L2E;
      }
      float p0 = exp2f(fmaf(s0.x, L2E, nmrl));
      float p1 = exp2f(fmaf(s0.y, L2E, nmrl));
      float p2 = exp2f(fmaf(s0.z, L2E, nmrl));
      float p3 = exp2f(fmaf(s0.w, L2E, nmrl));
      float p4 = exp2f(fmaf(s1.x, L2E, nmrl));
      float p5 = exp2f(fmaf(s1.y, L2E, nmrl));
      float p6 = exp2f(fmaf(s1.z, L2E, nmrl));
      float p7 = exp2f(fmaf(s1.w, L2E, nmrl));
      lrun += ((p0 + p1) + (p2 + p3)) + ((p4 + p5) + (p6 + p7));
      PF pf;
      asm("v_cvt_pk_bf16_f32 %0, %1, %2" : "=v"(pf.u[0]) : "v"(p0), "v"(p1));
      asm("v_cvt_pk_bf16_f32 %0, %1, %2" : "=v"(pf.u[1]) : "v"(p2), "v"(p3));
      asm("v_cvt_pk_bf16_f32 %0, %1, %2" : "=v"(pf.u[2]) : "v"(p4), "v"(p5));
      asm("v_cvt_pk_bf16_f32 %0, %1, %2" : "=v"(pf.u[3]) : "v"(p6), "v"(p7));
      Frag vf0, vf1;
      { const short* v0 = Vt + lr * VST + kv0 + 4 * g;
        vf0.h.lo = *(const s16x4*)v0; vf0.h.hi = *(const s16x4*)(v0 + 16);
        const short* v1 = Vt + (16 + lr) * VST + kv0 + 4 * g;
        vf1.h.lo = *(const s16x4*)v1; vf1.h.hi = *(const s16x4*)(v1 + 16); }
      // O^T = V^T . P^T : P frag comes straight from s0/s1 register layout
      o0 = __builtin_amdgcn_mfma_f32_16x16x32_bf16(vf0.v, pf.v, o0, 0,0,0);
      o1 = __builtin_amdgcn_mfma_f32_16x16x32_bf16(vf1.v, pf.v, o1, 0,0,0);
      mb0 = nb0; mb1 = nb1;
    }
    // combine per-lane partial sums across the 4 g-groups (once per tile)
    float lt = lrun + __shfl_xor(lrun, 16);
    lt += __shfl_xor(lt, 32);
    if (qrow < NTOK) {
      const float inv = 1.0f / lt;
      short* yb = y_ws + ((size_t)b * NTOK + qrow) * DIM + h * HD;
      s16x4 r0, r1;
      #pragma unroll
      for (int r = 0; r < 4; ++r) { r0[r] = f2bf(o0[r] * inv); r1[r] = f2bf(o1[r] * inv); }
      *(s16x4*)(yb + 4 * g) = r0;
      *(s16x4*)(yb + 16 + 4 * g) = r1;
    }
  }
}

// ---------------- K3: out = y @ proj_w^T + proj_b -----------------------------
// Swapped operands: lane owns 4 consecutive out channels -> f32x4 stores.
__global__ __launch_bounds__(256, 2)
void k_proj(const short* __restrict__ y_ws, const float* __restrict__ pw,
            const float* __restrict__ pb, float* __restrict__ out) {
  __shared__ short ys[64 * 136];
  __shared__ short wl[128 * 136];
  const int t = threadIdx.x;
  const int m0 = blockIdx.x * 64;
  {
    const int r = t >> 2, c0 = (t & 3) * 32;
    const s16x4* src = (const s16x4*)(y_ws + (size_t)(m0 + r) * DIM + c0);
    short* dst = ys + r * 136 + c0;
    #pragma unroll
    for (int i = 0; i < 8; ++i) *(s16x4*)(dst + 4*i) = src[i];
  }
  {
    const int r = t >> 1, c0 = (t & 1) * 64;
    const float* src = pw + (size_t)r * DIM + c0;
    short* dst = wl + r * 136 + c0;
    #pragma unroll
    for (int i = 0; i < 16; ++i)
      *(s16x4*)(dst + 4*i) = cvt4(*(const f32x4*)(src + 4*i));
  }
  __syncthreads();
  const int l = t & 63, w = t >> 6, lr = l & 15, g = l >> 4;
  const int m = m0 + w * 16 + lr;
  f32x4 acc[8] = {};
  #pragma unroll
  for (int ks = 0; ks < 4; ++ks) {
    const int k0 = ks * 32 + 4 * g;
    Frag ya;
    const short* bp = ys + (w * 16 + lr) * 136 + k0;
    ya.h.lo = *(const s16x4*)bp; ya.h.hi = *(const s16x4*)(bp + 16);
    #pragma unroll
    for (int ct = 0; ct < 8; ++ct) {
      const short* ap = wl + (ct * 16 + lr) * 136 + k0;
      Frag wa; wa.h.lo = *(const s16x4*)ap; wa.h.hi = *(const s16x4*)(ap + 16);
      acc[ct] = __builtin_amdgcn_mfma_f32_16x16x32_bf16(wa.v, ya.v, acc[ct], 0, 0, 0);
    }
  }
  #pragma unroll
  for (int ct = 0; ct < 8; ++ct) {
    const int c0 = ct * 16 + 4 * g;
    const f32x4 pbv = *(const f32x4*)(pb + c0);
    f32x4 res = acc[ct] + pbv;
    *(f32x4*)(out + (size_t)m * DIM + c0) = res;
  }
}

extern "C" void kernel_launch(void* const* d_in, const int* in_sizes, int n_in,
                              void* d_out, int out_size, void* d_ws, size_t ws_size,
                              hipStream_t stream) {
  const float* x    = (const float*)d_in[0];
  const float* mask = (const float*)d_in[1];
  const float* bt   = (const float*)d_in[2];
  const int*   ri   = (const int*)d_in[3];
  const float* qkvw = (const float*)d_in[4];
  const float* pw   = (const float*)d_in[5];
  const float* pb   = (const float*)d_in[6];
  float* out = (float*)d_out;
  // ws layout (bytes): 4 x 25.69MB bf16 tensors + 2.46MB bias = ~105.2MB
  const size_t TEN = (size_t)256 * NH * NTOK * HD;   // 12,845,056
  short* q_ws = (short*)d_ws;
  short* k_ws = q_ws + TEN;
  short* v_ws = k_ws + TEN;
  short* y_ws = v_ws + TEN;
  float* bias_pre = (float*)(y_ws + TEN);
  k_bias<<<(NTOK * NTOK + 255) / 256, 256, 0, stream>>>(bt, ri, bias_pre);
  k_qkv<<<1568, 256, 0, stream>>>(x, qkvw, q_ws, k_ws, v_ws);
  k_attn<<<1024, 512, 0, stream>>>(q_ws, k_ws, v_ws, mask, bias_pre, y_ws);
  k_proj<<<1568, 256, 0, stream>>>(y_ws, pw, pb, out);
}